// Round 4
// baseline (193.185 us; speedup 1.0000x reference)
//
#include <hip/hip_runtime.h>
#include <stdint.h>

typedef __attribute__((ext_vector_type(8))) short bf16x8;
typedef __attribute__((ext_vector_type(4))) float f32x4;

#define CC 256
#define HWP 65536

__device__ __forceinline__ unsigned short f2bf(float f) {
    union { float f; unsigned int u; } v; v.f = f;
    unsigned int u = v.u;
    return (unsigned short)((u + 0x7fffu + ((u >> 16) & 1u)) >> 16);
}
__device__ __forceinline__ unsigned int f2bf2(float lo, float hi) {
    return (unsigned)f2bf(lo) | ((unsigned)f2bf(hi) << 16);
}
__device__ __forceinline__ float sigm_relu(float xn) {
    float xr = fmaxf(xn, 0.f);
    float e = __expf(-xr);
    return __builtin_amdgcn_rcpf(1.f + e);
}

// ---- k1: 512 blocks x 512 thr, 256 px/block, float4 loads + LDS reduce ----
__global__ __launch_bounds__(512, 8) void k1_part(const float* __restrict__ x,
                                                  float* __restrict__ part) {
    __shared__ float red[8][520];
    const int t = threadIdx.x, bid = blockIdx.x;
    const int c4 = (t & 63) * 4, po = t >> 6;     // po 0..7
    const float* xp = x + ((size_t)(bid * 256 + po)) * CC + c4;
    f32x4 s = {0.f, 0.f, 0.f, 0.f}, q = {0.f, 0.f, 0.f, 0.f};
    #pragma unroll 8
    for (int p = 0; p < 32; ++p) {
        f32x4 v = *(const f32x4*)(xp + (size_t)p * 8 * CC);
        s += v; q += v * v;
    }
    *(f32x4*)&red[po][c4] = s;
    *(f32x4*)&red[po][256 + c4] = q;
    __syncthreads();
    float r = 0.f;
    #pragma unroll
    for (int po2 = 0; po2 < 8; ++po2) r += red[po2][t];
    part[bid * 512 + t] = r;
}

// ---- k2a: reduce 512 partial rows -> 32 rows ----
__global__ __launch_bounds__(256) void k2a_red(const float* __restrict__ part,
                                               float* __restrict__ p2) {
    int t = threadIdx.x, r = blockIdx.x;
    float s = 0.f, q = 0.f;
    #pragma unroll
    for (int i = 0; i < 16; ++i) {
        s += part[(size_t)(r * 16 + i) * 512 + t];
        q += part[(size_t)(r * 16 + i) * 512 + 256 + t];
    }
    p2[r * 512 + t] = s;
    p2[r * 512 + 256 + t] = q;
}

// ---- k2b: finalize mean / inv-std ----
__global__ __launch_bounds__(256) void k2b_stats(const float* __restrict__ p2,
                                                 float* __restrict__ mg,
                                                 float* __restrict__ ig) {
    int c = threadIdx.x;
    float s = 0.f, q = 0.f;
    #pragma unroll
    for (int r = 0; r < 32; ++r) { s += p2[r * 512 + c]; q += p2[r * 512 + 256 + c]; }
    float mean = s * (1.f / 131072.f);
    float var  = q * (1.f / 131072.f) - mean * mean;
    mg[c] = mean;
    ig[c] = rsqrtf(var + 1e-5f);
}

// ---- k3: Gram via MFMA, 512 thr, K split across wave pairs ----
__global__ __launch_bounds__(512, 6) void k3_gram(const float* __restrict__ x,
                                                  const float* __restrict__ wd,
                                                  const float* __restrict__ mg,
                                                  const float* __restrict__ ig,
                                                  float* __restrict__ gpart) {
    __shared__ uint4 apack[2048];        // [kb 0..31][n^kb 0..63], 32KB
    __shared__ float y_s[2][16][68];     // [k-half][o][px]
    const int t = threadIdx.x;
    const int w = t >> 6, lm = t & 15, lk = (t >> 4) & 3;
    const int h = w & 1, nt = w >> 1;    // k-half, px-tile
    // wd A-fragments for this wave's k-half (K rows h*128 .. +128)
    uint4 wfrag[4];
    #pragma unroll
    for (int kt = 0; kt < 4; ++kt) {
        const int kbr = h * 16 + kt * 4 + lk;
        f32x4 wa = *(const f32x4*)(wd + lm * 256 + kbr * 8);
        f32x4 wb = *(const f32x4*)(wd + lm * 256 + kbr * 8 + 4);
        wfrag[kt] = (uint4){f2bf2(wa[0], wa[1]), f2bf2(wa[2], wa[3]),
                            f2bf2(wb[0], wb[1]), f2bf2(wb[2], wb[3])};
    }
    // producer: a = sigmoid(relu(xn)) bf16 octets for 64 px (sample 0)
    {
        const int kb = t & 31, c0 = kb * 8, nb = t >> 5;   // nb 0..15
        f32x4 m0 = *(const f32x4*)(mg + c0), m1 = *(const f32x4*)(mg + c0 + 4);
        f32x4 i0 = *(const f32x4*)(ig + c0), i1 = *(const f32x4*)(ig + c0 + 4);
        float mm[8] = {m0[0],m0[1],m0[2],m0[3],m1[0],m1[1],m1[2],m1[3]};
        float ii[8] = {i0[0],i0[1],i0[2],i0[3],i1[0],i1[1],i1[2],i1[3]};
        const float* xb = x + ((size_t)(blockIdx.x * 64 + nb)) * CC + c0;
        #pragma unroll
        for (int rep = 0; rep < 4; ++rep) {
            int n = rep * 16 + nb;
            const float* xp = xb + (size_t)rep * 16 * CC;
            f32x4 v0 = *(const f32x4*)xp;
            f32x4 v1 = *(const f32x4*)(xp + 4);
            float vv[8] = {v0[0],v0[1],v0[2],v0[3],v1[0],v1[1],v1[2],v1[3]};
            unsigned aw[4];
            #pragma unroll
            for (int hh = 0; hh < 4; ++hh) {
                float a0 = sigm_relu((vv[2*hh]   - mm[2*hh])   * ii[2*hh]);
                float a1 = sigm_relu((vv[2*hh+1] - mm[2*hh+1]) * ii[2*hh+1]);
                aw[hh] = f2bf2(a0, a1);
            }
            apack[kb * 64 + (n ^ kb)] = (uint4){aw[0], aw[1], aw[2], aw[3]};
        }
    }
    __syncthreads();
    // Y-half[o][px tile nt]
    f32x4 accY = {0.f, 0.f, 0.f, 0.f};
    #pragma unroll
    for (int kt = 0; kt < 4; ++kt) {
        const int kbr = h * 16 + kt * 4 + lk;
        uint4 u = apack[kbr * 64 + ((nt * 16 + lm) ^ kbr)];
        accY = __builtin_amdgcn_mfma_f32_16x16x32_bf16(*(bf16x8*)&wfrag[kt], *(bf16x8*)&u, accY, 0, 0, 0);
    }
    #pragma unroll
    for (int i = 0; i < 4; ++i) y_s[h][lk * 4 + i][nt * 16 + lm] = accY[i];
    __syncthreads();
    // G-partial over 64 px, fp32
    if (t < 256) {
        const int o1 = t >> 4, o2 = t & 15;
        float g = 0.f;
        #pragma unroll
        for (int p4 = 0; p4 < 16; ++p4) {
            f32x4 a0 = *(const f32x4*)&y_s[0][o1][p4 * 4];
            f32x4 a1 = *(const f32x4*)&y_s[1][o1][p4 * 4];
            f32x4 b0 = *(const f32x4*)&y_s[0][o2][p4 * 4];
            f32x4 b1 = *(const f32x4*)&y_s[1][o2][p4 * 4];
            f32x4 ya = a0 + a1, yb = b0 + b1;
            g += ya[0]*yb[0] + ya[1]*yb[1] + ya[2]*yb[2] + ya[3]*yb[3];
        }
        gpart[blockIdx.x * 256 + t] = g;
    }
}

// ---- k4a: reduce 1024 Gram partial rows -> 64 ----
__global__ __launch_bounds__(256) void k4a_red(const float* __restrict__ gpart,
                                               float* __restrict__ g2) {
    int t = threadIdx.x, r = blockIdx.x;
    float g = 0.f;
    #pragma unroll
    for (int i = 0; i < 16; ++i) g += gpart[(size_t)(r * 16 + i) * 256 + t];
    g2[r * 256 + t] = g;
}

// ---- k4b: final G reduce + R = G0 @ w_down ----
__global__ __launch_bounds__(256) void k4b_R(const float* __restrict__ g2,
                                             const float* __restrict__ wd,
                                             float* __restrict__ Rg) {
    __shared__ float G_s[256];
    const int t = threadIdx.x;
    float g = 0.f;
    #pragma unroll
    for (int i = 0; i < 64; ++i) g += g2[i * 256 + t];
    G_s[t] = g;
    __syncthreads();
    #pragma unroll
    for (int o = 0; o < 16; ++o) {
        float r = 0.f;
        #pragma unroll
        for (int o2 = 0; o2 < 16; ++o2) r += G_s[o * 16 + o2] * wd[o2 * 256 + t];
        Rg[o * 256 + t] = r;
    }
}

// ---- k5: Wcb = [ Wf1 | (Wf2 @ w_up) @ R ]  in bf16, 256 x 512 ----
__global__ __launch_bounds__(256) void k5_wcb(const float* __restrict__ wf,
                                              const float* __restrict__ wu,
                                              const float* __restrict__ Rg,
                                              unsigned short* __restrict__ wcb) {
    __shared__ float M_s[16][17];
    const int t = threadIdx.x;
    const int lr = t >> 4, j = t & 15;
    const int r = blockIdx.x * 16 + lr;
    const float* wfr = wf + (size_t)r * 512;
    float m = 0.f;
    for (int c = 0; c < 256; ++c) m += wfr[256 + c] * wu[c * 16 + j];
    M_s[lr][j] = m;
    __syncthreads();
    float Ml[16];
    #pragma unroll
    for (int o = 0; o < 16; ++o) Ml[o] = M_s[lr][o];
    unsigned short* wrow = wcb + (size_t)r * 512;
    for (int i = 0; i < 16; ++i) {
        int c = j + 16 * i;
        wrow[c] = f2bf(wfr[c]);
        float kv = 0.f;
        #pragma unroll
        for (int o = 0; o < 16; ++o) kv += Ml[o] * Rg[o * 256 + c];
        wrow[256 + c] = f2bf(kv);
    }
}

// ---- k6: out = z x Wcb^T, 1024 thr / 64 px / block -> 32 waves/CU ----
__global__ __launch_bounds__(1024, 8) void k6_main(const float* __restrict__ x,
                                                   const unsigned short* __restrict__ wcb,
                                                   const float* __restrict__ mg,
                                                   const float* __restrict__ ig,
                                                   float* __restrict__ out) {
    __shared__ uint4 zpack[4096];   // [r 0..63][n^r 0..63] bf16 octets, 64KB
    const int t = threadIdx.x;
    const int tile = blockIdx.x;
    const int b = tile >> 10;
    const int pw = (tile & 1023) * 64;
    // producer: stage z=[xn;a] for 64 px
    {
        const int kb = t & 31, c0 = kb * 8, nb = t >> 5;   // nb 0..31
        f32x4 m0 = *(const f32x4*)(mg + c0), m1 = *(const f32x4*)(mg + c0 + 4);
        f32x4 i0 = *(const f32x4*)(ig + c0), i1 = *(const f32x4*)(ig + c0 + 4);
        float mm[8] = {m0[0],m0[1],m0[2],m0[3],m1[0],m1[1],m1[2],m1[3]};
        float ii[8] = {i0[0],i0[1],i0[2],i0[3],i1[0],i1[1],i1[2],i1[3]};
        const float* xb = x + ((size_t)(b * HWP + pw + nb)) * CC + c0;
        #pragma unroll
        for (int rep = 0; rep < 2; ++rep) {
            int n = rep * 32 + nb;
            const float* xp = xb + (size_t)rep * 32 * CC;
            f32x4 v0 = *(const f32x4*)xp;
            f32x4 v1 = *(const f32x4*)(xp + 4);
            float vv[8] = {v0[0],v0[1],v0[2],v0[3],v1[0],v1[1],v1[2],v1[3]};
            unsigned xw[4], aw[4];
            #pragma unroll
            for (int hh = 0; hh < 4; ++hh) {
                float xn0 = (vv[2*hh]   - mm[2*hh])   * ii[2*hh];
                float xn1 = (vv[2*hh+1] - mm[2*hh+1]) * ii[2*hh+1];
                xw[hh] = f2bf2(xn0, xn1);
                aw[hh] = f2bf2(sigm_relu(xn0), sigm_relu(xn1));
            }
            zpack[kb * 64 + (n ^ kb)] = (uint4){xw[0], xw[1], xw[2], xw[3]};
            zpack[(kb + 32) * 64 + (n ^ (kb + 32))] = (uint4){aw[0], aw[1], aw[2], aw[3]};
        }
    }
    __syncthreads();
    // consumer: wave w -> 16 channel rows x 64 px
    const int w = t >> 6, lm = t & 15, lk = (t >> 4) & 3;
    const unsigned short* wrow = wcb + (size_t)(w * 16 + lm) * 512 + lk * 8;
    float* outw = out + ((size_t)(b * 256 + w * 16 + lm)) * HWP + pw;
    f32x4 acc[4];
    #pragma unroll
    for (int mt = 0; mt < 4; ++mt) acc[mt] = (f32x4){0.f, 0.f, 0.f, 0.f};
    #pragma unroll 4
    for (int kt = 0; kt < 16; ++kt) {
        const int kbr = kt * 4 + lk;
        bf16x8 wfr = *(const bf16x8*)(wrow + kt * 32);
        #pragma unroll
        for (int mt = 0; mt < 4; ++mt) {
            uint4 u = zpack[kbr * 64 + ((mt * 16 + lm) ^ kbr)];
            acc[mt] = __builtin_amdgcn_mfma_f32_16x16x32_bf16(*(bf16x8*)&u, wfr, acc[mt], 0, 0, 0);
        }
    }
    #pragma unroll
    for (int mt = 0; mt < 4; ++mt)
        __builtin_nontemporal_store(acc[mt], (f32x4*)(outw + mt * 16 + lk * 4));
}

extern "C" void kernel_launch(void* const* d_in, const int* in_sizes, int n_in,
                              void* d_out, int out_size, void* d_ws, size_t ws_size,
                              hipStream_t stream) {
    const float* x  = (const float*)d_in[0];
    const float* wd = (const float*)d_in[1];
    const float* wu = (const float*)d_in[2];
    const float* wf = (const float*)d_in[3];
    float* out = (float*)d_out;
    char* ws = (char*)d_ws;
    unsigned short* wcb = (unsigned short*)ws;               // 256 KiB
    float* part  = (float*)(ws + 262144);                    // 1 MiB
    float* p2    = (float*)(ws + 262144 + 1048576);          // 64 KiB
    float* mg    = (float*)(ws + 1376256);                   // 1 KiB
    float* ig    = (float*)(ws + 1377280);                   // 1 KiB
    float* gpart = (float*)(ws + 1378304);                   // 1 MiB
    float* g2    = (float*)(ws + 2426880);                   // 64 KiB
    float* Rg    = (float*)(ws + 2492416);                   // 16 KiB

    k1_part <<<dim3(512),  dim3(512),  0, stream>>>(x, part);
    k2a_red <<<dim3(32),   dim3(256),  0, stream>>>(part, p2);
    k2b_stats<<<dim3(1),   dim3(256),  0, stream>>>(p2, mg, ig);
    k3_gram <<<dim3(1024), dim3(512),  0, stream>>>(x, wd, mg, ig, gpart);
    k4a_red <<<dim3(64),   dim3(256),  0, stream>>>(gpart, g2);
    k4b_R   <<<dim3(1),    dim3(256),  0, stream>>>(g2, wd, Rg);
    k5_wcb  <<<dim3(16),   dim3(256),  0, stream>>>(wf, wu, Rg, wcb);
    k6_main <<<dim3(2048), dim3(1024), 0, stream>>>(x, wcb, mg, ig, out);
}

// Round 5
// 175.778 us; speedup vs baseline: 1.0990x; 1.0990x over previous
//
#include <hip/hip_runtime.h>
#include <stdint.h>

typedef __attribute__((ext_vector_type(8))) short bf16x8;
typedef __attribute__((ext_vector_type(4))) float f32x4;

#define CC 256
#define HWP 65536

__device__ __forceinline__ unsigned short f2bf(float f) {
    union { float f; unsigned int u; } v; v.f = f;
    unsigned int u = v.u;
    return (unsigned short)((u + 0x7fffu + ((u >> 16) & 1u)) >> 16);
}
__device__ __forceinline__ unsigned int f2bf2(float lo, float hi) {
    return (unsigned)f2bf(lo) | ((unsigned)f2bf(hi) << 16);
}
__device__ __forceinline__ float sigm_relu(float xn) {
    float xr = fmaxf(xn, 0.f);
    float e = __expf(-xr);
    return __builtin_amdgcn_rcpf(1.f + e);
}

// ---- k1: 512 blocks x 512 thr, 256 px/block, float4 loads + LDS reduce ----
__global__ __launch_bounds__(512, 8) void k1_part(const float* __restrict__ x,
                                                  float* __restrict__ part) {
    __shared__ float red[8][520];
    const int t = threadIdx.x, bid = blockIdx.x;
    const int c4 = (t & 63) * 4, po = t >> 6;     // po 0..7
    const float* xp = x + ((size_t)(bid * 256 + po)) * CC + c4;
    f32x4 s = {0.f, 0.f, 0.f, 0.f}, q = {0.f, 0.f, 0.f, 0.f};
    #pragma unroll 8
    for (int p = 0; p < 32; ++p) {
        f32x4 v = *(const f32x4*)(xp + (size_t)p * 8 * CC);
        s += v; q += v * v;
    }
    *(f32x4*)&red[po][c4] = s;
    *(f32x4*)&red[po][256 + c4] = q;
    __syncthreads();
    float r = 0.f;
    #pragma unroll
    for (int po2 = 0; po2 < 8; ++po2) r += red[po2][t];
    part[bid * 512 + t] = r;
}

// ---- k2a: reduce 512 partial rows -> 32 rows ----
__global__ __launch_bounds__(256) void k2a_red(const float* __restrict__ part,
                                               float* __restrict__ p2) {
    int t = threadIdx.x, r = blockIdx.x;
    float s = 0.f, q = 0.f;
    #pragma unroll
    for (int i = 0; i < 16; ++i) {
        s += part[(size_t)(r * 16 + i) * 512 + t];
        q += part[(size_t)(r * 16 + i) * 512 + 256 + t];
    }
    p2[r * 512 + t] = s;
    p2[r * 512 + 256 + t] = q;
}

// ---- k2b: finalize mean / inv-std ----
__global__ __launch_bounds__(256) void k2b_stats(const float* __restrict__ p2,
                                                 float* __restrict__ mg,
                                                 float* __restrict__ ig) {
    int c = threadIdx.x;
    float s = 0.f, q = 0.f;
    #pragma unroll
    for (int r = 0; r < 32; ++r) { s += p2[r * 512 + c]; q += p2[r * 512 + 256 + c]; }
    float mean = s * (1.f / 131072.f);
    float var  = q * (1.f / 131072.f) - mean * mean;
    mg[c] = mean;
    ig[c] = rsqrtf(var + 1e-5f);
}

// ---- k3: Gram via MFMA, 256 blocks x 256 px (4 sub-tiles), K split over wave pairs ----
__global__ __launch_bounds__(512) void k3_gram(const float* __restrict__ x,
                                               const float* __restrict__ wd,
                                               const float* __restrict__ mg,
                                               const float* __restrict__ ig,
                                               float* __restrict__ gpart) {
    __shared__ uint4 apack[2048];        // [kb 0..31][n^kb 0..63], 32KB
    __shared__ float y_s[2][16][68];     // [k-half][o][px]
    const int t = threadIdx.x;
    const int w = t >> 6, lm = t & 15, lk = (t >> 4) & 3;
    const int h = w & 1, ntile = w >> 1;     // k-half, px-16-tile
    uint4 wfrag[4];
    #pragma unroll
    for (int kt = 0; kt < 4; ++kt) {
        const int kbr = h * 16 + kt * 4 + lk;
        f32x4 wa = *(const f32x4*)(wd + lm * 256 + kbr * 8);
        f32x4 wb = *(const f32x4*)(wd + lm * 256 + kbr * 8 + 4);
        wfrag[kt] = (uint4){f2bf2(wa[0], wa[1]), f2bf2(wa[2], wa[3]),
                            f2bf2(wb[0], wb[1]), f2bf2(wb[2], wb[3])};
    }
    const int kb = t & 31, c0 = kb * 8, nb = t >> 5;   // nb 0..15
    f32x4 m0 = *(const f32x4*)(mg + c0), m1 = *(const f32x4*)(mg + c0 + 4);
    f32x4 i0 = *(const f32x4*)(ig + c0), i1 = *(const f32x4*)(ig + c0 + 4);
    const float mm[8] = {m0[0],m0[1],m0[2],m0[3],m1[0],m1[1],m1[2],m1[3]};
    const float ii[8] = {i0[0],i0[1],i0[2],i0[3],i1[0],i1[1],i1[2],i1[3]};
    const int o1 = t >> 4, o2 = t & 15;   // gram pair (t < 256)
    float g = 0.f;
    for (int st = 0; st < 4; ++st) {
        const float* xb = x + ((size_t)(blockIdx.x * 256 + st * 64 + nb)) * CC + c0;
        #pragma unroll
        for (int rep = 0; rep < 4; ++rep) {
            int n = rep * 16 + nb;
            const float* xp = xb + (size_t)rep * 16 * CC;
            f32x4 v0 = *(const f32x4*)xp;
            f32x4 v1 = *(const f32x4*)(xp + 4);
            float vv[8] = {v0[0],v0[1],v0[2],v0[3],v1[0],v1[1],v1[2],v1[3]};
            unsigned aw[4];
            #pragma unroll
            for (int hh = 0; hh < 4; ++hh) {
                float a0 = sigm_relu((vv[2*hh]   - mm[2*hh])   * ii[2*hh]);
                float a1 = sigm_relu((vv[2*hh+1] - mm[2*hh+1]) * ii[2*hh+1]);
                aw[hh] = f2bf2(a0, a1);
            }
            apack[kb * 64 + (n ^ kb)] = (uint4){aw[0], aw[1], aw[2], aw[3]};
        }
        __syncthreads();
        f32x4 accY = {0.f, 0.f, 0.f, 0.f};
        #pragma unroll
        for (int kt = 0; kt < 4; ++kt) {
            const int kbr = h * 16 + kt * 4 + lk;
            uint4 u = apack[kbr * 64 + ((ntile * 16 + lm) ^ kbr)];
            accY = __builtin_amdgcn_mfma_f32_16x16x32_bf16(*(bf16x8*)&wfrag[kt], *(bf16x8*)&u, accY, 0, 0, 0);
        }
        #pragma unroll
        for (int i = 0; i < 4; ++i) y_s[h][lk * 4 + i][ntile * 16 + lm] = accY[i];
        __syncthreads();
        if (t < 256) {
            #pragma unroll
            for (int p4 = 0; p4 < 16; ++p4) {
                f32x4 a0 = *(const f32x4*)&y_s[0][o1][p4 * 4];
                f32x4 a1 = *(const f32x4*)&y_s[1][o1][p4 * 4];
                f32x4 b0 = *(const f32x4*)&y_s[0][o2][p4 * 4];
                f32x4 b1 = *(const f32x4*)&y_s[1][o2][p4 * 4];
                f32x4 ya = a0 + a1, yb = b0 + b1;
                g += ya[0]*yb[0] + ya[1]*yb[1] + ya[2]*yb[2] + ya[3]*yb[3];
            }
        }
        __syncthreads();
    }
    if (t < 256) gpart[blockIdx.x * 256 + t] = g;
}

// ---- k4: reduce 256 Gram partial rows + R = G0 @ w_down ----
__global__ __launch_bounds__(256) void k4_R(const float* __restrict__ gpart,
                                            const float* __restrict__ wd,
                                            float* __restrict__ Rg) {
    __shared__ float G_s[256];
    const int t = threadIdx.x;
    float g = 0.f;
    #pragma unroll 8
    for (int i = 0; i < 256; ++i) g += gpart[i * 256 + t];
    G_s[t] = g;
    __syncthreads();
    #pragma unroll
    for (int o = 0; o < 16; ++o) {
        float r = 0.f;
        #pragma unroll
        for (int o2 = 0; o2 < 16; ++o2) r += G_s[o * 16 + o2] * wd[o2 * 256 + t];
        Rg[o * 256 + t] = r;
    }
}

// ---- k5: Wcb = [ Wf1 | (Wf2 @ w_up) @ R ]  in bf16, 256 x 512 ----
__global__ __launch_bounds__(256) void k5_wcb(const float* __restrict__ wf,
                                              const float* __restrict__ wu,
                                              const float* __restrict__ Rg,
                                              unsigned short* __restrict__ wcb) {
    __shared__ float M_s[16][17];
    const int t = threadIdx.x;
    const int lr = t >> 4, j = t & 15;
    const int r = blockIdx.x * 16 + lr;
    const float* wfr = wf + (size_t)r * 512;
    float m = 0.f;
    for (int c = 0; c < 256; ++c) m += wfr[256 + c] * wu[c * 16 + j];
    M_s[lr][j] = m;
    __syncthreads();
    float Ml[16];
    #pragma unroll
    for (int o = 0; o < 16; ++o) Ml[o] = M_s[lr][o];
    unsigned short* wrow = wcb + (size_t)r * 512;
    for (int i = 0; i < 16; ++i) {
        int c = j + 16 * i;
        wrow[c] = f2bf(wfr[c]);
        float kv = 0.f;
        #pragma unroll
        for (int o = 0; o < 16; ++o) kv += Ml[o] * Rg[o * 256 + c];
        wrow[256 + c] = f2bf(kv);
    }
}

// ---- k6: out = z x Wcb^T, 512 thr / 64 px; LDS-transposed coalesced epilogue ----
__global__ __launch_bounds__(512, 4) void k6_main(const float* __restrict__ x,
                                                  const unsigned short* __restrict__ wcb,
                                                  const float* __restrict__ mg,
                                                  const float* __restrict__ ig,
                                                  float* __restrict__ out) {
    __shared__ __align__(16) char smem[69632];   // union: zpack 64KB | T 256x68 fp32
    uint4* zpack = (uint4*)smem;                 // [kb 0..63][n^kb 0..63]
    float* T = (float*)smem;                     // [ch][68] fp32, px 0..63
    const int t = threadIdx.x;
    const int tile = blockIdx.x;
    const int b = tile >> 10;
    const int pw = (tile & 1023) * 64;
    // producer: stage z=[xn;a] for 64 px
    {
        const int kb = t & 31, c0 = kb * 8, nb = t >> 5;   // nb 0..15
        f32x4 m0 = *(const f32x4*)(mg + c0), m1 = *(const f32x4*)(mg + c0 + 4);
        f32x4 i0 = *(const f32x4*)(ig + c0), i1 = *(const f32x4*)(ig + c0 + 4);
        float mm[8] = {m0[0],m0[1],m0[2],m0[3],m1[0],m1[1],m1[2],m1[3]};
        float ii[8] = {i0[0],i0[1],i0[2],i0[3],i1[0],i1[1],i1[2],i1[3]};
        const float* xb = x + ((size_t)(b * HWP + pw + nb)) * CC + c0;
        #pragma unroll
        for (int rep = 0; rep < 4; ++rep) {
            int n = rep * 16 + nb;
            const float* xp = xb + (size_t)rep * 16 * CC;
            f32x4 v0 = *(const f32x4*)xp;
            f32x4 v1 = *(const f32x4*)(xp + 4);
            float vv[8] = {v0[0],v0[1],v0[2],v0[3],v1[0],v1[1],v1[2],v1[3]};
            unsigned xw[4], aw[4];
            #pragma unroll
            for (int hh = 0; hh < 4; ++hh) {
                float xn0 = (vv[2*hh]   - mm[2*hh])   * ii[2*hh];
                float xn1 = (vv[2*hh+1] - mm[2*hh+1]) * ii[2*hh+1];
                xw[hh] = f2bf2(xn0, xn1);
                aw[hh] = f2bf2(sigm_relu(xn0), sigm_relu(xn1));
            }
            zpack[kb * 64 + (n ^ kb)] = (uint4){xw[0], xw[1], xw[2], xw[3]};
            zpack[(kb + 32) * 64 + (n ^ (kb + 32))] = (uint4){aw[0], aw[1], aw[2], aw[3]};
        }
    }
    __syncthreads();
    // consumer: wave w -> ch rows w*32..+32, px 0..63
    const int w = t >> 6, lm = t & 15, lk = (t >> 4) & 3;
    const unsigned short* wrow = wcb + (size_t)(w * 32 + lm) * 512 + lk * 8;
    f32x4 acc[4][2];
    #pragma unroll
    for (int mt = 0; mt < 4; ++mt)
        #pragma unroll
        for (int nt = 0; nt < 2; ++nt) acc[mt][nt] = (f32x4){0.f, 0.f, 0.f, 0.f};
    #pragma unroll 4
    for (int kt = 0; kt < 16; ++kt) {
        const int kbr = kt * 4 + lk;
        bf16x8 zfr[4], wfr[2];
        #pragma unroll
        for (int mt = 0; mt < 4; ++mt) {
            uint4 u = zpack[kbr * 64 + ((mt * 16 + lm) ^ kbr)];
            zfr[mt] = *(bf16x8*)&u;
        }
        #pragma unroll
        for (int nt = 0; nt < 2; ++nt)
            wfr[nt] = *(const bf16x8*)(wrow + (size_t)nt * 16 * 512 + kt * 32);
        #pragma unroll
        for (int mt = 0; mt < 4; ++mt)
            #pragma unroll
            for (int nt = 0; nt < 2; ++nt)
                acc[mt][nt] = __builtin_amdgcn_mfma_f32_16x16x32_bf16(zfr[mt], wfr[nt], acc[mt][nt], 0, 0, 0);
    }
    __syncthreads();   // all zpack reads done; reuse smem as T
    // stash D tile: T[ch][px], ch = w*32 + nt*16 + lm, px = mt*16 + lk*4 + i
    #pragma unroll
    for (int nt = 0; nt < 2; ++nt) {
        const int ch = w * 32 + nt * 16 + lm;
        #pragma unroll
        for (int mt = 0; mt < 4; ++mt)
            *(f32x4*)&T[ch * 68 + mt * 16 + lk * 4] = acc[mt][nt];
    }
    __syncthreads();
    // coalesced store: per iteration 32 rows x 256B contiguous
    {
        const int row0 = t >> 4, pxq = t & 15;
        float* ob = out + (size_t)b * 256 * HWP + pw + pxq * 4;
        #pragma unroll
        for (int j = 0; j < 8; ++j) {
            const int row = j * 32 + row0;
            f32x4 v = *(const f32x4*)&T[row * 68 + pxq * 4];
            __builtin_nontemporal_store(v, (f32x4*)(ob + (size_t)row * HWP));
        }
    }
}

extern "C" void kernel_launch(void* const* d_in, const int* in_sizes, int n_in,
                              void* d_out, int out_size, void* d_ws, size_t ws_size,
                              hipStream_t stream) {
    const float* x  = (const float*)d_in[0];
    const float* wd = (const float*)d_in[1];
    const float* wu = (const float*)d_in[2];
    const float* wf = (const float*)d_in[3];
    float* out = (float*)d_out;
    char* ws = (char*)d_ws;
    unsigned short* wcb = (unsigned short*)ws;               // 256 KiB
    float* part  = (float*)(ws + 262144);                    // 1 MiB
    float* p2    = (float*)(ws + 1310720);                   // 64 KiB
    float* mg    = (float*)(ws + 1376256);                   // 1 KiB
    float* ig    = (float*)(ws + 1377280);                   // 1 KiB
    float* gpart = (float*)(ws + 1378304);                   // 256 KiB
    float* Rg    = (float*)(ws + 1640448);                   // 16 KiB

    k1_part <<<dim3(512),  dim3(512), 0, stream>>>(x, part);
    k2a_red <<<dim3(32),   dim3(256), 0, stream>>>(part, p2);
    k2b_stats<<<dim3(1),   dim3(256), 0, stream>>>(p2, mg, ig);
    k3_gram <<<dim3(256),  dim3(512), 0, stream>>>(x, wd, mg, ig, gpart);
    k4_R    <<<dim3(1),    dim3(256), 0, stream>>>(gpart, wd, Rg);
    k5_wcb  <<<dim3(16),   dim3(256), 0, stream>>>(wf, wu, Rg, wcb);
    k6_main <<<dim3(2048), dim3(512), 0, stream>>>(x, wcb, mg, ig, out);
}